// Round 1
// baseline (189.586 us; speedup 1.0000x reference)
//
#include <hip/hip_runtime.h>

// Problem constants (B=2, S=2048, D=1024, H=16, HD=64, W=128 from reference)
#define S_LEN 2048
#define DMODEL 1024
#define NHEAD 16
#define HDIM 64

typedef __bf16 bf16x8 __attribute__((ext_vector_type(8)));
typedef float f32x4 __attribute__((ext_vector_type(4)));

typedef __attribute__((address_space(1))) const void gconst_void;
typedef __attribute__((address_space(3))) void lds_void;

__device__ __forceinline__ unsigned short f2bf(float f) {
    unsigned u = __builtin_bit_cast(unsigned, f);
    u += 0x7fffu + ((u >> 16) & 1u);   // RNE
    return (unsigned short)(u >> 16);
}

// ---------------- fp32 -> bf16 convert (vectorized) ----------------
__global__ __launch_bounds__(256) void cvt_f32_bf16(const float* __restrict__ src,
                                                    unsigned short* __restrict__ dst, int n4) {
    int i = blockIdx.x * 256 + threadIdx.x;
    if (i < n4) {
        float4 f = ((const float4*)src)[i];
        ushort4 o;
        o.x = f2bf(f.x); o.y = f2bf(f.y); o.z = f2bf(f.z); o.w = f2bf(f.w);
        ((ushort4*)dst)[i] = o;
    }
}

// ---------------- GEMM: C[M,N] = A[M,K] * Bt[N,K]^T + bias ----------------
// m97-style: 128x128 tile, BK=64, global_load_lds width 16, XOR chunk swizzle.
// QKV_MODE=1: out is bf16, cols < DMODEL (q) scaled by 0.125. QKV_MODE=0: fp32 out.
template <int QKV_MODE>
__global__ __launch_bounds__(256) void gemm_bt(const unsigned short* __restrict__ A,
                                               const unsigned short* __restrict__ Bt,
                                               const float* __restrict__ bias,
                                               void* __restrict__ out,
                                               int M, int N, int K) {
    __shared__ unsigned short lA[128 * 64] __attribute__((aligned(16)));
    __shared__ unsigned short lB[128 * 64] __attribute__((aligned(16)));

    const int tid  = threadIdx.x;
    const int lane = tid & 63;
    const int w    = tid >> 6;
    const int quad = lane >> 4;
    const int l16  = lane & 15;

    const int m0 = blockIdx.x * 128;
    const int n0 = blockIdx.y * 128;

    // staging: thread -> (row 0..31 within pass, swizzled chunk)
    const int rowi = tid >> 3;                           // 0..31
    const int csw  = ((tid & 7) ^ (rowi & 7)) * 8;       // swizzled source chunk (elements)
    const unsigned short* aSrc = A + (size_t)(m0 + rowi) * K + csw;
    const unsigned short* bSrc = Bt + (size_t)(n0 + rowi) * K + csw;
    const int dstOff = (w * 8) * 64;                     // wave-uniform LDS base (elements)

    f32x4 acc[4][4];
    {
        f32x4 z = {0.f, 0.f, 0.f, 0.f};
        #pragma unroll
        for (int i = 0; i < 4; i++)
            #pragma unroll
            for (int j = 0; j < 4; j++) acc[i][j] = z;
    }

    const int wm = (w & 1) * 64;
    const int wn = (w >> 1) * 64;

    for (int kt = 0; kt < K; kt += 64) {
        __syncthreads();
        #pragma unroll
        for (int p = 0; p < 4; p++) {
            __builtin_amdgcn_global_load_lds(
                (gconst_void*)(aSrc + (size_t)p * 32 * K + kt),
                (lds_void*)(&lA[dstOff + p * 32 * 64]), 16, 0, 0);
            __builtin_amdgcn_global_load_lds(
                (gconst_void*)(bSrc + (size_t)p * 32 * K + kt),
                (lds_void*)(&lB[dstOff + p * 32 * 64]), 16, 0, 0);
        }
        __syncthreads();

        #pragma unroll
        for (int kk = 0; kk < 2; kk++) {
            bf16x8 af[4], bfr[4];
            const int xsw = ((kk * 4 + quad) ^ (l16 & 7)) * 8;
            #pragma unroll
            for (int t = 0; t < 4; t++) {
                af[t]  = *(const bf16x8*)&lA[(wm + t * 16 + l16) * 64 + xsw];
                bfr[t] = *(const bf16x8*)&lB[(wn + t * 16 + l16) * 64 + xsw];
            }
            #pragma unroll
            for (int i = 0; i < 4; i++)
                #pragma unroll
                for (int j = 0; j < 4; j++)
                    acc[i][j] = __builtin_amdgcn_mfma_f32_16x16x32_bf16(af[i], bfr[j], acc[i][j], 0, 0, 0);
        }
    }

    // epilogue: C/D layout col=lane&15, row=quad*4+reg  [m89]
    #pragma unroll
    for (int j = 0; j < 4; j++) {
        const int n = n0 + wn + j * 16 + l16;
        const float bv = bias[n];
        float scl = 1.0f;
        if (QKV_MODE) scl = (n < DMODEL) ? 0.125f : 1.0f;
        #pragma unroll
        for (int i = 0; i < 4; i++) {
            const int mrow = m0 + wm + i * 16 + quad * 4;
            #pragma unroll
            for (int r = 0; r < 4; r++) {
                float v = (acc[i][j][r] + bv) * scl;
                if (QKV_MODE)
                    ((unsigned short*)out)[(size_t)(mrow + r) * N + n] = f2bf(v);
                else
                    ((float*)out)[(size_t)(mrow + r) * N + n] = v;
            }
        }
    }
}

// ---------------- windowed flash attention ----------------
// block = (q-tile of 64, head, batch); 4 waves, wave w owns queries w*16..w*16+15.
__global__ __launch_bounds__(256) void attn_win(const unsigned short* __restrict__ qkv, // [B*S, 3D] bf16
                                                unsigned short* __restrict__ attnout,   // [B*S, D] bf16
                                                const int* __restrict__ wptr) {
    __shared__ unsigned short lK[32 * 64] __attribute__((aligned(16)));   // [key][d], chunk-swizzled
    __shared__ unsigned short lV[64 * 32] __attribute__((aligned(16)));   // [d][key] (transposed), swizzled
    __shared__ unsigned short lP[4][16 * 32] __attribute__((aligned(16))); // per-wave P, swizzled

    const int W = wptr[0];
    const int tid  = threadIdx.x;
    const int lane = tid & 63;
    const int w    = tid >> 6;
    const int quad = lane >> 4;
    const int l16  = lane & 15;

    const int q0 = blockIdx.x * 64;
    const int h  = blockIdx.y;
    const size_t rowbase = (size_t)blockIdx.z * S_LEN;

    // Q fragments (A-layout: m=lane&15, k=quad*8+j) — q pre-scaled by 0.125 in GEMM1
    const int qrow = q0 + w * 16 + l16;
    bf16x8 qf0, qf1;
    {
        const unsigned short* qp = qkv + (rowbase + qrow) * (3 * DMODEL) + h * HDIM;
        qf0 = *(const bf16x8*)(qp + quad * 8);
        qf1 = *(const bf16x8*)(qp + 32 + quad * 8);
    }

    f32x4 o[4];
    { f32x4 z = {0.f,0.f,0.f,0.f}; o[0]=z; o[1]=z; o[2]=z; o[3]=z; }
    float mrow[4], lrow[4];
    #pragma unroll
    for (int r = 0; r < 4; r++) { mrow[r] = -1e30f; lrow[r] = 0.f; }

    const int kbase = q0 - W;
    const int nch = (2 * W + 64 + 31) / 32;

    const int skey = tid >> 3;  // staging: key 0..31
    const int sci  = tid & 7;   // staging: 16B chunk 0..7
    const int iq = q0 + w * 16 + quad * 4;

    for (int c = 0; c < nch; c++) {
        const int kc0 = kbase + c * 32;
        __syncthreads();
        {   // stage K chunk [32 keys x 64 d] and V chunk transposed [64 d x 32 keys]
            int kg = kc0 + skey;
            int kcl = kg < 0 ? 0 : (kg > S_LEN - 1 ? S_LEN - 1 : kg);
            const unsigned short* kp = qkv + (rowbase + kcl) * (3 * DMODEL) + DMODEL + h * HDIM + sci * 8;
            int4 kd = *(const int4*)kp;
            *(int4*)&lK[skey * 64 + ((sci ^ (skey & 7)) * 8)] = kd;

            const unsigned short* vp = qkv + (rowbase + kcl) * (3 * DMODEL) + 2 * DMODEL + h * HDIM + sci * 8;
            int4 vd = *(const int4*)vp;
            unsigned short ve[8];
            *(int4*)ve = vd;
            #pragma unroll
            for (int j = 0; j < 8; j++) {
                int d = sci * 8 + j;
                int pos = ((skey >> 3) ^ ((d >> 1) & 3)) & 3;
                lV[d * 32 + pos * 8 + (skey & 7)] = ve[j];
            }
        }
        __syncthreads();

        // S = Q K^T  (two 16-key tiles, two 32-d K-steps)
        f32x4 s0 = {0.f,0.f,0.f,0.f}, s1 = {0.f,0.f,0.f,0.f};
        {
            int xk0 = ((quad) ^ (l16 & 7)) * 8;
            int xk1 = ((4 + quad) ^ (l16 & 7)) * 8;
            bf16x8 k00 = *(const bf16x8*)&lK[(l16) * 64 + xk0];
            bf16x8 k01 = *(const bf16x8*)&lK[(l16) * 64 + xk1];
            bf16x8 k10 = *(const bf16x8*)&lK[(16 + l16) * 64 + xk0];
            bf16x8 k11 = *(const bf16x8*)&lK[(16 + l16) * 64 + xk1];
            s0 = __builtin_amdgcn_mfma_f32_16x16x32_bf16(qf0, k00, s0, 0, 0, 0);
            s0 = __builtin_amdgcn_mfma_f32_16x16x32_bf16(qf1, k01, s0, 0, 0, 0);
            s1 = __builtin_amdgcn_mfma_f32_16x16x32_bf16(qf0, k10, s1, 0, 0, 0);
            s1 = __builtin_amdgcn_mfma_f32_16x16x32_bf16(qf1, k11, s1, 0, 0, 0);
        }

        // online softmax per q-row (row lives in the 16 lanes of this quad-group)
        const int j0 = kc0 + l16;
        const int j1 = j0 + 16;
        #pragma unroll
        for (int r = 0; r < 4; r++) {
            const int i = iq + r;
            const int d0 = i - j0, d1 = i - j1;
            const bool v0 = ((unsigned)j0 < (unsigned)S_LEN) && (d0 <= W) && (-d0 <= W);
            const bool v1 = ((unsigned)j1 < (unsigned)S_LEN) && (d1 <= W) && (-d1 <= W);
            float sv0 = v0 ? s0[r] : -1e30f;
            float sv1 = v1 ? s1[r] : -1e30f;
            float mc = fmaxf(sv0, sv1);
            mc = fmaxf(mc, __shfl_xor(mc, 1));
            mc = fmaxf(mc, __shfl_xor(mc, 2));
            mc = fmaxf(mc, __shfl_xor(mc, 4));
            mc = fmaxf(mc, __shfl_xor(mc, 8));
            float mnew = fmaxf(mrow[r], mc);
            float alpha = __expf(mrow[r] - mnew);
            float p0 = v0 ? __expf(s0[r] - mnew) : 0.f;
            float p1 = v1 ? __expf(s1[r] - mnew) : 0.f;
            float ps = p0 + p1;
            ps += __shfl_xor(ps, 1);
            ps += __shfl_xor(ps, 2);
            ps += __shfl_xor(ps, 4);
            ps += __shfl_xor(ps, 8);
            lrow[r] = lrow[r] * alpha + ps;
            mrow[r] = mnew;
            o[0][r] *= alpha; o[1][r] *= alpha; o[2][r] *= alpha; o[3][r] *= alpha;
            // P -> LDS (C-layout -> row-major [q][32], chunk-swizzled by (q>>1)&3)
            const int qq = quad * 4 + r;
            const int sw = (qq >> 1) & 3;
            lP[w][qq * 32 + (((l16 >> 3) ^ sw) & 3) * 8 + (l16 & 7)] = f2bf(p0);
            lP[w][qq * 32 + ((((l16 >> 3) + 2) ^ sw) & 3) * 8 + (l16 & 7)] = f2bf(p1);
        }

        __builtin_amdgcn_s_waitcnt(0);  // wave-local LDS RAW (lockstep wave; no barrier needed)

        // O += P V  (A-layout P from LDS, B-layout V from transposed LDS)
        bf16x8 pf = *(const bf16x8*)&lP[w][l16 * 32 + ((quad ^ ((l16 >> 1) & 3)) & 3) * 8];
        #pragma unroll
        for (int t = 0; t < 4; t++) {
            const int d = t * 16 + l16;
            const int pos = (quad ^ ((d >> 1) & 3)) & 3;
            bf16x8 vf = *(const bf16x8*)&lV[d * 32 + pos * 8];
            o[t] = __builtin_amdgcn_mfma_f32_16x16x32_bf16(pf, vf, o[t], 0, 0, 0);
        }
    }

    // normalize + store bf16 (output layout [B,S,H*HD] == [B,S,D])
    #pragma unroll
    for (int r = 0; r < 4; r++) {
        const float inv = 1.f / lrow[r];
        #pragma unroll
        for (int t = 0; t < 4; t++) {
            attnout[(rowbase + iq + r) * DMODEL + h * HDIM + t * 16 + l16] = f2bf(o[t][r] * inv);
        }
    }
}

// ---------------- launch ----------------
extern "C" void kernel_launch(void* const* d_in, const int* in_sizes, int n_in,
                              void* d_out, int out_size, void* d_ws, size_t ws_size,
                              hipStream_t stream) {
    const float* x   = (const float*)d_in[0];  // [2,2048,1024]
    const float* w1  = (const float*)d_in[1];  // [3072,1024]
    const float* b1  = (const float*)d_in[2];  // [3072]
    const float* w2  = (const float*)d_in[3];  // [1024,1024]
    const float* b2  = (const float*)d_in[4];  // [1024]
    const int* wsz   = (const int*)d_in[5];    // window_size

    // workspace layout (40 MB): attn-out reuses the x_bf16 region (x consumed by GEMM1)
    char* ws = (char*)d_ws;
    unsigned short* xb    = (unsigned short*)(ws);                       // 8 MB
    unsigned short* attnb = (unsigned short*)(ws);                       // 8 MB (reuse)
    unsigned short* w1b   = (unsigned short*)(ws + (8u << 20));          // 6 MB
    unsigned short* w2b   = (unsigned short*)(ws + (14u << 20));         // 2 MB
    unsigned short* qkvb  = (unsigned short*)(ws + (16u << 20));         // 24 MB

    const int M = 2 * S_LEN;  // 4096

    cvt_f32_bf16<<<(M * DMODEL / 4 + 255) / 256, 256, 0, stream>>>(x, xb, M * DMODEL / 4);
    cvt_f32_bf16<<<(3 * DMODEL * DMODEL / 4 + 255) / 256, 256, 0, stream>>>(w1, w1b, 3 * DMODEL * DMODEL / 4);
    cvt_f32_bf16<<<(DMODEL * DMODEL / 4 + 255) / 256, 256, 0, stream>>>(w2, w2b, DMODEL * DMODEL / 4);

    gemm_bt<1><<<dim3(M / 128, 3 * DMODEL / 128), 256, 0, stream>>>(xb, w1b, b1, qkvb, M, 3 * DMODEL, DMODEL);

    attn_win<<<dim3(S_LEN / 64, NHEAD, 2), 256, 0, stream>>>(qkvb, attnb, wsz);

    gemm_bt<0><<<dim3(M / 128, DMODEL / 128), 256, 0, stream>>>(attnb, w2b, b2, (float*)d_out, M, DMODEL, DMODEL);
}